// Round 1
// baseline (861.533 us; speedup 1.0000x reference)
//
#include <hip/hip_runtime.h>
#include <hip/hip_bf16.h>

// Problem constants (B=16384, H=1024 fixed by the reference).
#define B_ROWS 16384
#define HDIM   1024
#define KDIM   2048   // 2*H  (d_t || h_prev along K)
#define NDIM   5120   // 5*H  (gates i,f,o,c,g along N)

typedef __attribute__((ext_vector_type(8))) __bf16 bf16x8;
typedef __attribute__((ext_vector_type(4))) float  f32x4;

// ---- workspace layout (all 256B aligned) ----
// [0,            67108864)   A packed bf16 [16384][2048]
// [67108864,     88080384)   B packed bf16 [5120][2048]   (B^T layout: [n][k])
// [88080384,     88100864)   bias fp32 [5120]
// [88100864,    255873024)   P = activated gates bf16 [16384][5120]
#define WS_OFF_B    67108864UL
#define WS_OFF_BIAS 88080384UL
#define WS_OFF_P    88100864UL

__device__ __forceinline__ void async16(const void* g, void* l) {
  __builtin_amdgcn_global_load_lds(
      (__attribute__((address_space(1))) void*)(g),
      (__attribute__((address_space(3))) void*)(l), 16, 0, 0);
}

__device__ __forceinline__ float fast_sigmoid(float x) {
  return 1.0f / (1.0f + __expf(-x));
}
__device__ __forceinline__ float fast_tanh(float x) {
  // 1 - 2/(e^{2x}+1); saturates correctly at +-1 for |x| large.
  return 1.0f - 2.0f / (__expf(2.0f * x) + 1.0f);
}

struct GatePtrs {
  const float* W[5];
  const float* U[5];
  const float* b[5];
};

// ---------- phase 1: fp32 -> bf16 packing ----------
// A[r][c] = c<1024 ? d_t[r][c] : h_prev[r][c-1024]
__global__ __launch_bounds__(256) void pack_A(const float* __restrict__ d,
                                              const float* __restrict__ h,
                                              __bf16* __restrict__ A) {
  const int idx = blockIdx.x * 256 + threadIdx.x;
  const size_t flat = (size_t)idx * 8;
  const int r = (int)(flat >> 11);
  const int c = (int)(flat & 2047);
  const float* src = (c < HDIM) ? (d + (size_t)r * HDIM + c)
                                : (h + (size_t)r * HDIM + (c - HDIM));
  const float4 v0 = ((const float4*)src)[0];
  const float4 v1 = ((const float4*)src)[1];
  bf16x8 o;
  o[0] = (__bf16)v0.x; o[1] = (__bf16)v0.y; o[2] = (__bf16)v0.z; o[3] = (__bf16)v0.w;
  o[4] = (__bf16)v1.x; o[5] = (__bf16)v1.y; o[6] = (__bf16)v1.z; o[7] = (__bf16)v1.w;
  *(bf16x8*)(A + flat) = o;
}

// Bm[row][c]: gate g = row>>10, out oo = row&1023; c<1024 -> W_g[oo][c], else U_g[oo][c-1024]
__global__ __launch_bounds__(256) void pack_B(GatePtrs gp, __bf16* __restrict__ Bm) {
  const int idx = blockIdx.x * 256 + threadIdx.x;
  const size_t flat = (size_t)idx * 8;
  const int row = (int)(flat >> 11);  // block-uniform (2048 elems = 1 row per block)
  const int c = (int)(flat & 2047);
  const int g = row >> 10;
  const int oo = row & 1023;
  const float* base = (c < HDIM) ? gp.W[g] : gp.U[g];
  const float* src = base + (size_t)oo * HDIM + (c & 1023);
  const float4 v0 = ((const float4*)src)[0];
  const float4 v1 = ((const float4*)src)[1];
  bf16x8 o;
  o[0] = (__bf16)v0.x; o[1] = (__bf16)v0.y; o[2] = (__bf16)v0.z; o[3] = (__bf16)v0.w;
  o[4] = (__bf16)v1.x; o[5] = (__bf16)v1.y; o[6] = (__bf16)v1.z; o[7] = (__bf16)v1.w;
  *(bf16x8*)(Bm + flat) = o;
}

__global__ __launch_bounds__(256) void pack_bias(GatePtrs gp, float* __restrict__ bias) {
  const int i = blockIdx.x * 256 + threadIdx.x;  // 0..5119
  bias[i] = gp.b[i >> 10][i & 1023];
}

// ---------- phase 2: fused GEMM + bias + activation ----------
// C[m][n] = act( sum_k A[m][k]*Bm[n][k] + bias[n] ), act = tanh for gate 3 else sigmoid.
// m97 structure: 128x128 tile, BK=64, 4 waves of 64x64, 16x16x32 bf16 MFMA,
// global_load_lds width=16 staging (contiguous LDS, no padding).
__global__ __launch_bounds__(256) void gemm_act(const __bf16* __restrict__ A,
                                                const __bf16* __restrict__ Bm,
                                                const float* __restrict__ bias,
                                                __bf16* __restrict__ P) {
  __shared__ __align__(16) __bf16 As[128 * 64];
  __shared__ __align__(16) __bf16 Bs[128 * 64];

  const int tid  = threadIdx.x;
  const int lane = tid & 63;
  const int wave = tid >> 6;
  const int quad = lane >> 4;   // 0..3
  const int lr   = lane & 15;   // row-in-16 (A/m), col-in-16 (B/n, C col)
  const int wm   = (wave >> 1) << 6;  // 0 or 64
  const int wn   = (wave & 1) << 6;   // 0 or 64

  const int row0 = blockIdx.x * 128;
  const int col0 = blockIdx.y * 128;

  f32x4 acc[4][4] = {};

  for (int kt = 0; kt < KDIM; kt += 64) {
    // stage 128x64 A-tile and B-tile: 1024 16B-chunks each tile section
    // chunk c = t*256+tid; lds dest = base + lane*16 (wave-uniform base per (t,wave))
#pragma unroll
    for (int t = 0; t < 4; ++t) {
      const int c  = t * 256 + tid;
      const int r  = c >> 3;
      const int k8 = (c & 7) * 8;
      async16(A  + (size_t)(row0 + r) * KDIM + kt + k8, As + c * 8);
      async16(Bm + (size_t)(col0 + r) * KDIM + kt + k8, Bs + c * 8);
    }
    __syncthreads();  // compiler emits vmcnt(0) drain before s_barrier

#pragma unroll
    for (int kk = 0; kk < 64; kk += 32) {
      bf16x8 af[4], bf[4];
#pragma unroll
      for (int i = 0; i < 4; ++i)
        af[i] = *(const bf16x8*)(As + (wm + i * 16 + lr) * 64 + kk + quad * 8);
#pragma unroll
      for (int i = 0; i < 4; ++i)
        bf[i] = *(const bf16x8*)(Bs + (wn + i * 16 + lr) * 64 + kk + quad * 8);
#pragma unroll
      for (int i = 0; i < 4; ++i)
#pragma unroll
        for (int j = 0; j < 4; ++j)
          acc[i][j] = __builtin_amdgcn_mfma_f32_16x16x32_bf16(af[i], bf[j], acc[i][j], 0, 0, 0);
    }
    __syncthreads();
  }

  // Epilogue. C/D layout (m89/m91 verified): col = lane&15, row = quad*4 + reg.
  const int gate = col0 >> 10;  // 128-col tile never crosses a gate boundary
#pragma unroll
  for (int i = 0; i < 4; ++i) {
    const int grow = row0 + wm + i * 16 + quad * 4;
#pragma unroll
    for (int j = 0; j < 4; ++j) {
      const int gcol = col0 + wn + j * 16 + lr;
      const float bv = bias[gcol];
#pragma unroll
      for (int r = 0; r < 4; ++r) {
        const float v = acc[i][j][r] + bv;
        const float a = (gate == 3) ? fast_tanh(v) : fast_sigmoid(v);
        P[(size_t)(grow + r) * NDIM + gcol] = (__bf16)a;
      }
    }
  }
}

// ---------- phase 3: cell update + per-row fraction + outputs ----------
// one block per row; 256 threads x 4 cols each
__global__ __launch_bounds__(256) void fuse_out(const __bf16* __restrict__ P,
                                                const float* __restrict__ cprev,
                                                float* __restrict__ h_out,
                                                float* __restrict__ c_out) {
  const int r = blockIdx.x;
  const int t = threadIdx.x;
  const __bf16* Pr = P + (size_t)r * NDIM;
  const float* cpr = cprev + (size_t)r * HDIM;

  float ct[4], cp[4], ov[4], gv[4];
  float num = 0.f, den = 0.f;
#pragma unroll
  for (int q = 0; q < 4; ++q) {
    const int c = t + q * 256;
    const float iv = (float)Pr[c];
    const float fv = (float)Pr[HDIM + c];
    ov[q] = (float)Pr[2 * HDIM + c];
    const float ch = (float)Pr[3 * HDIM + c];
    gv[q] = (float)Pr[4 * HDIM + c];
    cp[q] = cpr[c];
    ct[q] = iv * ch + fv * cp[q];
    num += ct[q] * cp[q];
    den += cp[q] * cp[q];
  }
  // wave (64-lane) shuffle reduce, then cross-wave via LDS
#pragma unroll
  for (int off = 32; off > 0; off >>= 1) {
    num += __shfl_down(num, off);
    den += __shfl_down(den, off);
  }
  __shared__ float sn[4], sd[4];
  const int lane = t & 63, wave = t >> 6;
  if (lane == 0) { sn[wave] = num; sd[wave] = den; }
  __syncthreads();
  const float frac = (sn[0] + sn[1] + sn[2] + sn[3]) /
                     (sd[0] + sd[1] + sd[2] + sd[3]);
#pragma unroll
  for (int q = 0; q < 4; ++q) {
    const int c = t + q * 256;
    const float cd = ct[q] - gv[q] * frac * cp[q];
    h_out[(size_t)r * HDIM + c] = ov[q] * fast_tanh(cd);
    c_out[(size_t)r * HDIM + c] = ct[q];
  }
}

extern "C" void kernel_launch(void* const* d_in, const int* in_sizes, int n_in,
                              void* d_out, int out_size, void* d_ws, size_t ws_size,
                              hipStream_t stream) {
  const float* d_t    = (const float*)d_in[0];
  const float* h_prev = (const float*)d_in[1];
  const float* c_prev = (const float*)d_in[2];
  GatePtrs gp;
  for (int g = 0; g < 5; ++g) {
    gp.W[g] = (const float*)d_in[3 + g * 3];
    gp.b[g] = (const float*)d_in[4 + g * 3];
    gp.U[g] = (const float*)d_in[5 + g * 3];
  }

  char* ws = (char*)d_ws;
  __bf16* Apack  = (__bf16*)ws;
  __bf16* Bpack  = (__bf16*)(ws + WS_OFF_B);
  float*  biasA  = (float*)(ws + WS_OFF_BIAS);
  __bf16* P      = (__bf16*)(ws + WS_OFF_P);

  float* h_out = (float*)d_out;
  float* c_out = h_out + (size_t)B_ROWS * HDIM;

  pack_A<<<dim3(B_ROWS * (KDIM / 2048)), 256, 0, stream>>>(d_t, h_prev, Apack);           // 16384 blocks
  pack_B<<<dim3(NDIM), 256, 0, stream>>>(gp, Bpack);                                      // 5120 blocks
  pack_bias<<<dim3(NDIM / 256), 256, 0, stream>>>(gp, biasA);                             // 20 blocks
  gemm_act<<<dim3(B_ROWS / 128, NDIM / 128), 256, 0, stream>>>(Apack, Bpack, biasA, P);   // 128 x 40
  fuse_out<<<dim3(B_ROWS), 256, 0, stream>>>(P, c_prev, h_out, c_out);                    // 16384 blocks
}

// Round 2
// 772.977 us; speedup vs baseline: 1.1146x; 1.1146x over previous
//
#include <hip/hip_runtime.h>
#include <hip/hip_bf16.h>

// Problem constants (B=16384, H=1024 fixed by the reference).
#define B_ROWS 16384
#define HDIM   1024
#define KDIM   2048   // 2*H  (d_t || h_prev along K)
#define NDIM   5120   // 5*H  (gates i,f,o,c,g along N)

typedef __attribute__((ext_vector_type(8))) __bf16 bf16x8;
typedef __attribute__((ext_vector_type(4))) float  f32x4;

// ---- workspace layout (all 256B aligned) ----
// [0,            67108864)   A packed bf16 [16384][2048]
// [67108864,     88080384)   B packed bf16 [5120][2048]   (B^T layout: [n][k])
// [88080384,     88100864)   bias fp32 [5120]
// [88100864,    255873024)   P = activated gates bf16 [16384][5120]
#define WS_OFF_B    67108864UL
#define WS_OFF_BIAS 88080384UL
#define WS_OFF_P    88100864UL

__device__ __forceinline__ void async16(const void* g, void* l) {
  __builtin_amdgcn_global_load_lds(
      (__attribute__((address_space(1))) void*)(g),
      (__attribute__((address_space(3))) void*)(l), 16, 0, 0);
}

__device__ __forceinline__ float fast_sigmoid(float x) {
  return 1.0f / (1.0f + __expf(-x));
}
__device__ __forceinline__ float fast_tanh(float x) {
  // 1 - 2/(e^{2x}+1); saturates correctly at +-1 for |x| large.
  return 1.0f - 2.0f / (__expf(2.0f * x) + 1.0f);
}

struct GatePtrs {
  const float* W[5];
  const float* U[5];
  const float* b[5];
};

// ---------- phase 1: fp32 -> bf16 packing ----------
// A[r][c] = c<1024 ? d_t[r][c] : h_prev[r][c-1024]
__global__ __launch_bounds__(256) void pack_A(const float* __restrict__ d,
                                              const float* __restrict__ h,
                                              __bf16* __restrict__ A) {
  const int idx = blockIdx.x * 256 + threadIdx.x;
  const size_t flat = (size_t)idx * 8;
  const int r = (int)(flat >> 11);
  const int c = (int)(flat & 2047);
  const float* src = (c < HDIM) ? (d + (size_t)r * HDIM + c)
                                : (h + (size_t)r * HDIM + (c - HDIM));
  const float4 v0 = ((const float4*)src)[0];
  const float4 v1 = ((const float4*)src)[1];
  bf16x8 o;
  o[0] = (__bf16)v0.x; o[1] = (__bf16)v0.y; o[2] = (__bf16)v0.z; o[3] = (__bf16)v0.w;
  o[4] = (__bf16)v1.x; o[5] = (__bf16)v1.y; o[6] = (__bf16)v1.z; o[7] = (__bf16)v1.w;
  *(bf16x8*)(A + flat) = o;
}

// Bm[row][c]: gate g = row>>10, out oo = row&1023; c<1024 -> W_g[oo][c], else U_g[oo][c-1024]
__global__ __launch_bounds__(256) void pack_B(GatePtrs gp, __bf16* __restrict__ Bm) {
  const int idx = blockIdx.x * 256 + threadIdx.x;
  const size_t flat = (size_t)idx * 8;
  const int row = (int)(flat >> 11);  // block-uniform (2048 elems = 1 row per block)
  const int c = (int)(flat & 2047);
  const int g = row >> 10;
  const int oo = row & 1023;
  const float* base = (c < HDIM) ? gp.W[g] : gp.U[g];
  const float* src = base + (size_t)oo * HDIM + (c & 1023);
  const float4 v0 = ((const float4*)src)[0];
  const float4 v1 = ((const float4*)src)[1];
  bf16x8 o;
  o[0] = (__bf16)v0.x; o[1] = (__bf16)v0.y; o[2] = (__bf16)v0.z; o[3] = (__bf16)v0.w;
  o[4] = (__bf16)v1.x; o[5] = (__bf16)v1.y; o[6] = (__bf16)v1.z; o[7] = (__bf16)v1.w;
  *(bf16x8*)(Bm + flat) = o;
}

__global__ __launch_bounds__(256) void pack_bias(GatePtrs gp, float* __restrict__ bias) {
  const int i = blockIdx.x * 256 + threadIdx.x;  // 0..5119
  bias[i] = gp.b[i >> 10][i & 1023];
}

// ---------- phase 2: fused GEMM + bias + activation ----------
// C[m][n] = act( sum_k A[m][k]*Bm[n][k] + bias[n] ), act = tanh for gate 3 else sigmoid.
// m97 structure: 128x128 tile, BK=64, 4 waves of 64x64, 16x16x32 bf16 MFMA,
// global_load_lds width=16 staging.
//
// LDS layout is XOR-swizzled: slot (row r, chunk p) holds global chunk p^(r&7)
// of that row. Row stride = 128 B = full bank wrap, so the un-swizzled
// fragment read (all 16 lanes of a quarter-wave at the same chunk) was a
// 16-way bank conflict (+12 cyc/ds_read_b128, SQ_LDS_BANK_CONFLICT=1.26e8).
// The swizzle spreads each quarter-wave across all 8 chunk positions
// (2 lanes per 4-bank group = free 2-way). global_load_lds forces the LDS
// dest to wave-uniform-base + lane*16, so the permutation is applied to the
// *source* address (bijection within each 128 B row -> coalescing unchanged).
__global__ __launch_bounds__(256) void gemm_act(const __bf16* __restrict__ A,
                                                const __bf16* __restrict__ Bm,
                                                const float* __restrict__ bias,
                                                __bf16* __restrict__ P) {
  __shared__ __align__(16) __bf16 As[128 * 64];
  __shared__ __align__(16) __bf16 Bs[128 * 64];

  const int tid  = threadIdx.x;
  const int lane = tid & 63;
  const int wave = tid >> 6;
  const int quad = lane >> 4;   // 0..3
  const int lr   = lane & 15;   // row-in-16 (A/m), col-in-16 (B/n, C col)
  const int sx   = lr & 7;      // swizzle key for fragment reads
  const int wm   = (wave >> 1) << 6;  // 0 or 64
  const int wn   = (wave & 1) << 6;   // 0 or 64

  const int row0 = blockIdx.x * 128;
  const int col0 = blockIdx.y * 128;

  f32x4 acc[4][4] = {};

  for (int kt = 0; kt < KDIM; kt += 64) {
    // stage 128x64 A-tile and B-tile: 1024 16B-chunks each tile section.
    // LDS slot c = t*256+tid -> (row c>>3, chunk c&7); source chunk is
    // (c&7)^(row&7) (XOR swizzle).
#pragma unroll
    for (int t = 0; t < 4; ++t) {
      const int c  = t * 256 + tid;
      const int r  = c >> 3;
      const int q  = (c & 7) ^ (r & 7);
      async16(A  + (size_t)(row0 + r) * KDIM + kt + q * 8, As + c * 8);
      async16(Bm + (size_t)(col0 + r) * KDIM + kt + q * 8, Bs + c * 8);
    }
    __syncthreads();  // compiler emits vmcnt(0) drain before s_barrier

#pragma unroll
    for (int kk = 0; kk < 64; kk += 32) {
      const int kq = (kk >> 3) + quad;  // logical chunk index for this frag
      bf16x8 af[4], bf[4];
#pragma unroll
      for (int i = 0; i < 4; ++i)
        af[i] = *(const bf16x8*)(As + (wm + i * 16 + lr) * 64 + ((kq ^ sx) << 3));
#pragma unroll
      for (int i = 0; i < 4; ++i)
        bf[i] = *(const bf16x8*)(Bs + (wn + i * 16 + lr) * 64 + ((kq ^ sx) << 3));
#pragma unroll
      for (int i = 0; i < 4; ++i)
#pragma unroll
        for (int j = 0; j < 4; ++j)
          acc[i][j] = __builtin_amdgcn_mfma_f32_16x16x32_bf16(af[i], bf[j], acc[i][j], 0, 0, 0);
    }
    __syncthreads();
  }

  // Epilogue. C/D layout (m89/m91 verified): col = lane&15, row = quad*4 + reg.
  const int gate = col0 >> 10;  // 128-col tile never crosses a gate boundary
#pragma unroll
  for (int i = 0; i < 4; ++i) {
    const int grow = row0 + wm + i * 16 + quad * 4;
#pragma unroll
    for (int j = 0; j < 4; ++j) {
      const int gcol = col0 + wn + j * 16 + lr;
      const float bv = bias[gcol];
#pragma unroll
      for (int r = 0; r < 4; ++r) {
        const float v = acc[i][j][r] + bv;
        const float a = (gate == 3) ? fast_tanh(v) : fast_sigmoid(v);
        P[(size_t)(grow + r) * NDIM + gcol] = (__bf16)a;
      }
    }
  }
}

// ---------- phase 3: cell update + per-row fraction + outputs ----------
// one block per row; 256 threads x 4 cols each
__global__ __launch_bounds__(256) void fuse_out(const __bf16* __restrict__ P,
                                                const float* __restrict__ cprev,
                                                float* __restrict__ h_out,
                                                float* __restrict__ c_out) {
  const int r = blockIdx.x;
  const int t = threadIdx.x;
  const __bf16* Pr = P + (size_t)r * NDIM;
  const float* cpr = cprev + (size_t)r * HDIM;

  float ct[4], cp[4], ov[4], gv[4];
  float num = 0.f, den = 0.f;
#pragma unroll
  for (int q = 0; q < 4; ++q) {
    const int c = t + q * 256;
    const float iv = (float)Pr[c];
    const float fv = (float)Pr[HDIM + c];
    ov[q] = (float)Pr[2 * HDIM + c];
    const float ch = (float)Pr[3 * HDIM + c];
    gv[q] = (float)Pr[4 * HDIM + c];
    cp[q] = cpr[c];
    ct[q] = iv * ch + fv * cp[q];
    num += ct[q] * cp[q];
    den += cp[q] * cp[q];
  }
  // wave (64-lane) shuffle reduce, then cross-wave via LDS
#pragma unroll
  for (int off = 32; off > 0; off >>= 1) {
    num += __shfl_down(num, off);
    den += __shfl_down(den, off);
  }
  __shared__ float sn[4], sd[4];
  const int lane = t & 63, wave = t >> 6;
  if (lane == 0) { sn[wave] = num; sd[wave] = den; }
  __syncthreads();
  const float frac = (sn[0] + sn[1] + sn[2] + sn[3]) /
                     (sd[0] + sd[1] + sd[2] + sd[3]);
#pragma unroll
  for (int q = 0; q < 4; ++q) {
    const int c = t + q * 256;
    const float cd = ct[q] - gv[q] * frac * cp[q];
    h_out[(size_t)r * HDIM + c] = ov[q] * fast_tanh(cd);
    c_out[(size_t)r * HDIM + c] = ct[q];
  }
}

extern "C" void kernel_launch(void* const* d_in, const int* in_sizes, int n_in,
                              void* d_out, int out_size, void* d_ws, size_t ws_size,
                              hipStream_t stream) {
  const float* d_t    = (const float*)d_in[0];
  const float* h_prev = (const float*)d_in[1];
  const float* c_prev = (const float*)d_in[2];
  GatePtrs gp;
  for (int g = 0; g < 5; ++g) {
    gp.W[g] = (const float*)d_in[3 + g * 3];
    gp.b[g] = (const float*)d_in[4 + g * 3];
    gp.U[g] = (const float*)d_in[5 + g * 3];
  }

  char* ws = (char*)d_ws;
  __bf16* Apack  = (__bf16*)ws;
  __bf16* Bpack  = (__bf16*)(ws + WS_OFF_B);
  float*  biasA  = (float*)(ws + WS_OFF_BIAS);
  __bf16* P      = (__bf16*)(ws + WS_OFF_P);

  float* h_out = (float*)d_out;
  float* c_out = h_out + (size_t)B_ROWS * HDIM;

  pack_A<<<dim3(B_ROWS * (KDIM / 2048)), 256, 0, stream>>>(d_t, h_prev, Apack);           // 16384 blocks
  pack_B<<<dim3(NDIM), 256, 0, stream>>>(gp, Bpack);                                      // 5120 blocks
  pack_bias<<<dim3(NDIM / 256), 256, 0, stream>>>(gp, biasA);                             // 20 blocks
  gemm_act<<<dim3(B_ROWS / 128, NDIM / 128), 256, 0, stream>>>(Apack, Bpack, biasA, P);   // 128 x 40
  fuse_out<<<dim3(B_ROWS), 256, 0, stream>>>(P, c_prev, h_out, c_out);                    // 16384 blocks
}